// Round 7
// baseline (355.144 us; speedup 1.0000x reference)
//
#include <hip/hip_runtime.h>
#include <hip/hip_bf16.h>

typedef __hip_bfloat16 bf16;

#define P_CNT 16
#define J_CNT 23
#define VPT   4            // verts per thread
#define VB    1024         // 256 threads x VPT verts per block

struct PosePtrs { const void* p[11]; };

__device__ const int   c_par[J_CNT]  = {-1,0,1,1,3,4,5,4,7,4,9,1,11,12,13,12,15,12,17,0,19,0,21};
__device__ const int   c_slot[J_CNT] = {0,-1,-1,1,2,3,-1,4,-1,5,-1,6,7,8,-1,9,-1,10,-1,-1,-1,-1,-1};
__device__ const float c_scale[11]   = {
    0.7853981633974483f, 1.5707963267948966f, 1.5707963267948966f, 0.7853981633974483f,
    0.7853981633974483f, 0.7853981633974483f, 1.5707963267948966f, 1.5707963267948966f,
    0.7853981633974483f, 0.7853981633974483f, 0.7853981633974483f};

template <bool BF>
__device__ __forceinline__ float ld(const void* p, long long i) {
    if (BF) return __bfloat162float(((const bf16*)p)[i]);
    return ((const float*)p)[i];
}
template <bool BF>
__device__ __forceinline__ void st(void* p, long long i, float v) {
    if (BF) ((bf16*)p)[i] = __float2bfloat16(v);
    else    ((float*)p)[i] = v;
}
__device__ __forceinline__ float bflo(unsigned u) { return __uint_as_float(u << 16); }
__device__ __forceinline__ float bfhi(unsigned u) { return __uint_as_float(u & 0xffff0000u); }
__device__ __forceinline__ unsigned packbf(float a, float b) {
    bf16 ha = __float2bfloat16(a), hb = __float2bfloat16(b);
    unsigned short ua, ub;
    __builtin_memcpy(&ua, &ha, 2); __builtin_memcpy(&ub, &hb, 2);
    return ((unsigned)ub << 16) | (unsigned)ua;
}

template <bool BF>
__device__ __forceinline__ void run(const void* __restrict__ verts,
                                    const void* __restrict__ joints,
                                    const void* __restrict__ weights,
                                    const void* __restrict__ disp,
                                    const void* __restrict__ rdis,
                                    const PosePtrs pp,
                                    void* __restrict__ out, int V,
                                    float* __restrict__ sA,
                                    float* __restrict__ sPose,
                                    float* __restrict__ sSh)
{
    const int t = threadIdx.x;
    const long long vb = (long long)blockIdx.x * VB;

    // ---- stage pose params -> LDS (compile-time slot index: no kernarg
    //      dynamic indexing -> no scratch) ----
#pragma unroll
    for (int s = 0; s < 11; ++s) {
        if (t < P_CNT * 3) sPose[s * (P_CNT * 3) + t] = ld<BF>(pp.p[s], t);
    }
    if (t < P_CNT) {
#pragma unroll
        for (int cc = 0; cc < 3; ++cc)
            sSh[t * 3 + cc] = ld<BF>(rdis, t * 3 + cc) + 3.f * tanhf(ld<BF>(disp, t * 3 + cc));
    }
    __syncthreads();

    // ---- phase 1: per-(p,j) local transforms T=[R|t] by ALL threads ----
#pragma unroll 1
    for (int idx = t; idx < P_CNT * J_CNT; idx += 256) {
        int pq = idx / J_CNT, j = idx - pq * J_CNT;
        float rx = 0.f, ry = 0.f, rz = 0.f;
        int s = c_slot[j];
        if (s >= 0) {
            float sc = c_scale[s];
            rx = sc * tanhf(sPose[s * (P_CNT * 3) + pq * 3 + 0]);
            ry = sc * tanhf(sPose[s * (P_CNT * 3) + pq * 3 + 1]);
            rz = sc * tanhf(sPose[s * (P_CNT * 3) + pq * 3 + 2]);
        }
        float ang = sqrtf(rx * rx + ry * ry + rz * rz + 1e-16f);
        float sn = sinf(ang), cs = cosf(ang);
        float C = 1.f - cs, inva = 1.f / ang;
        float x = rx * inva, y = ry * inva, z = rz * inva;
        float t0 = ld<BF>(joints, j * 3 + 0);
        float t1 = ld<BF>(joints, j * 3 + 1);
        float t2 = ld<BF>(joints, j * 3 + 2);
        if (j != 0) {
            int q = c_par[j];
            t0 -= ld<BF>(joints, q * 3 + 0);
            t1 -= ld<BF>(joints, q * 3 + 1);
            t2 -= ld<BF>(joints, q * 3 + 2);
        }
        float* Ar = sA + idx * 12;
        Ar[0]  = 1.f - C * (y * y + z * z); Ar[1]  = -sn * z + C * x * y;       Ar[2]  = sn * y + C * x * z;        Ar[3]  = t0;
        Ar[4]  = sn * z + C * x * y;        Ar[5]  = 1.f - C * (x * x + z * z); Ar[6]  = -sn * x + C * y * z;       Ar[7]  = t1;
        Ar[8]  = -sn * y + C * x * z;       Ar[9]  = sn * x + C * y * z;        Ar[10] = 1.f - C * (x * x + y * y); Ar[11] = t2;
    }
    __syncthreads();

    // ---- phase 2: chain composition in-place (16 lanes, own pose only) ----
    if (t < P_CNT) {
        float* Gp = sA + t * (J_CNT * 12);
#pragma unroll 1
        for (int j = 1; j < J_CNT; ++j) {
            const float* Gq = Gp + c_par[j] * 12;
            float* Tj = Gp + j * 12;
            float4 gq0 = *(const float4*)(Gq + 0);
            float4 gq1 = *(const float4*)(Gq + 4);
            float4 gq2 = *(const float4*)(Gq + 8);
            float4 r0 = *(const float4*)(Tj + 0);
            float4 r1 = *(const float4*)(Tj + 4);
            float4 r2 = *(const float4*)(Tj + 8);
            float4 o0, o1, o2;
            o0.x = gq0.x*r0.x + gq0.y*r1.x + gq0.z*r2.x;
            o0.y = gq0.x*r0.y + gq0.y*r1.y + gq0.z*r2.y;
            o0.z = gq0.x*r0.z + gq0.y*r1.z + gq0.z*r2.z;
            o0.w = gq0.x*r0.w + gq0.y*r1.w + gq0.z*r2.w + gq0.w;
            o1.x = gq1.x*r0.x + gq1.y*r1.x + gq1.z*r2.x;
            o1.y = gq1.x*r0.y + gq1.y*r1.y + gq1.z*r2.y;
            o1.z = gq1.x*r0.z + gq1.y*r1.z + gq1.z*r2.z;
            o1.w = gq1.x*r0.w + gq1.y*r1.w + gq1.z*r2.w + gq1.w;
            o2.x = gq2.x*r0.x + gq2.y*r1.x + gq2.z*r2.x;
            o2.y = gq2.x*r0.y + gq2.y*r1.y + gq2.z*r2.y;
            o2.z = gq2.x*r0.z + gq2.y*r1.z + gq2.z*r2.z;
            o2.w = gq2.x*r0.w + gq2.y*r1.w + gq2.z*r2.w + gq2.w;
            *(float4*)(Tj + 0) = o0;
            *(float4*)(Tj + 4) = o1;
            *(float4*)(Tj + 8) = o2;
        }
    }
    __syncthreads();

    // ---- phase 3: G -> A in place (t' = t - R*j); block 0 writes out1 ----
    {
        const long long pv3 = (long long)P_CNT * V * 3;
#pragma unroll 1
        for (int idx = t; idx < P_CNT * J_CNT; idx += 256) {
            int pq = idx / J_CNT, j = idx - pq * J_CNT;
            float jx = ld<BF>(joints, j * 3 + 0);
            float jy = ld<BF>(joints, j * 3 + 1);
            float jz = ld<BF>(joints, j * 3 + 2);
            float* Ar = sA + idx * 12;
            float g03 = Ar[3], g13 = Ar[7], g23 = Ar[11];
            Ar[3]  = g03 - (Ar[0] * jx + Ar[1] * jy + Ar[2]  * jz);
            Ar[7]  = g13 - (Ar[4] * jx + Ar[5] * jy + Ar[6]  * jz);
            Ar[11] = g23 - (Ar[8] * jx + Ar[9] * jy + Ar[10] * jz);
            if (blockIdx.x == 0) {
                void* out1 = BF ? (void*)((bf16*)out + pv3) : (void*)((float*)out + pv3);
                st<BF>(out1, (long long)idx * 3 + 0, g03 + sSh[pq * 3 + 0]);
                st<BF>(out1, (long long)idx * 3 + 1, g13 + sSh[pq * 3 + 1]);
                st<BF>(out1, (long long)idx * 3 + 2, g23 + sSh[pq * 3 + 2]);
            }
        }
    }
    __syncthreads();

    // ---- main: VPT verts/thread; A broadcast from LDS amortized over VPT ----
    const long long v0 = vb + (long long)t * VPT;
    if (v0 >= (long long)V) return;
    const bool full = ((v0 + VPT) <= (long long)V) && ((V & 3) == 0);

    // w and positions fully register-resident; ALL indices compile-time.
    float w[VPT * J_CNT];          // 92 floats
    float px[VPT], py[VPT], pz[VPT];

    if (full) {
        if (!BF) {
            const float4* wp = (const float4*)((const float*)weights + v0 * J_CNT);
#pragma unroll
            for (int k = 0; k < J_CNT; ++k) {      // 23 x float4 = 92 floats
                float4 q = wp[k];
                w[4*k+0] = q.x; w[4*k+1] = q.y; w[4*k+2] = q.z; w[4*k+3] = q.w;
            }
            const float4* vp = (const float4*)((const float*)verts + v0 * 3);
            float4 q0 = vp[0], q1 = vp[1], q2 = vp[2];
            px[0] = q0.x; py[0] = q0.y; pz[0] = q0.z;
            px[1] = q0.w; py[1] = q1.x; pz[1] = q1.y;
            px[2] = q1.z; py[2] = q1.w; pz[2] = q2.x;
            px[3] = q2.y; py[3] = q2.z; pz[3] = q2.w;
        } else {
            const uint2* wp = (const uint2*)((const bf16*)weights + v0 * J_CNT);
#pragma unroll
            for (int k = 0; k < J_CNT; ++k) {      // 23 x uint2 = 92 bf16
                uint2 u = wp[k];
                w[4*k+0] = bflo(u.x); w[4*k+1] = bfhi(u.x);
                w[4*k+2] = bflo(u.y); w[4*k+3] = bfhi(u.y);
            }
            const uint2* vp = (const uint2*)((const bf16*)verts + v0 * 3);
            uint2 u0 = vp[0], u1 = vp[1], u2 = vp[2];
            px[0] = bflo(u0.x); py[0] = bfhi(u0.x); pz[0] = bflo(u0.y);
            px[1] = bfhi(u0.y); py[1] = bflo(u1.x); pz[1] = bfhi(u1.x);
            px[2] = bflo(u1.y); py[2] = bfhi(u1.y); pz[2] = bflo(u2.x);
            px[3] = bfhi(u2.x); py[3] = bflo(u2.y); pz[3] = bfhi(u2.y);
        }
    } else {
#pragma unroll
        for (int v = 0; v < VPT; ++v) {
            bool ok = (v0 + v) < (long long)V;
            px[v] = ok ? ld<BF>(verts, (v0 + v) * 3 + 0) : 0.f;
            py[v] = ok ? ld<BF>(verts, (v0 + v) * 3 + 1) : 0.f;
            pz[v] = ok ? ld<BF>(verts, (v0 + v) * 3 + 2) : 0.f;
#pragma unroll
            for (int j = 0; j < J_CNT; ++j)
                w[v * J_CNT + j] = ok ? ld<BF>(weights, (v0 + v) * J_CNT + j) : 0.f;
        }
    }

    const float4* A4 = (const float4*)sA;
#pragma unroll 1
    for (int p = 0; p < P_CNT; ++p) {
        const float4* Ap = A4 + p * (J_CNT * 3);
        float ox[VPT], oy[VPT], oz[VPT];
#pragma unroll
        for (int v = 0; v < VPT; ++v) { ox[v] = 0.f; oy[v] = 0.f; oz[v] = 0.f; }
#pragma unroll
        for (int j = 0; j < J_CNT; ++j) {          // FULLY unrolled: w idx static
            float4 a0 = Ap[j * 3 + 0], a1 = Ap[j * 3 + 1], a2 = Ap[j * 3 + 2];
#pragma unroll
            for (int v = 0; v < VPT; ++v) {
                float d0 = fmaf(a0.x, px[v], fmaf(a0.y, py[v], fmaf(a0.z, pz[v], a0.w)));
                float d1 = fmaf(a1.x, px[v], fmaf(a1.y, py[v], fmaf(a1.z, pz[v], a1.w)));
                float d2 = fmaf(a2.x, px[v], fmaf(a2.y, py[v], fmaf(a2.z, pz[v], a2.w)));
                float wv = w[v * J_CNT + j];
                ox[v] = fmaf(wv, d0, ox[v]);
                oy[v] = fmaf(wv, d1, oy[v]);
                oz[v] = fmaf(wv, d2, oz[v]);
            }
        }
        const float shx = sSh[p * 3 + 0], shy = sSh[p * 3 + 1], shz = sSh[p * 3 + 2];
#pragma unroll
        for (int v = 0; v < VPT; ++v) { ox[v] += shx; oy[v] += shy; oz[v] += shz; }

        const long long base = ((long long)p * V + v0) * 3;
        if (!BF) {
            if (full) {
                float4* op = (float4*)((float*)out + base);   // 48B-aligned: v0%4==0
                op[0] = make_float4(ox[0], oy[0], oz[0], ox[1]);
                op[1] = make_float4(oy[1], oz[1], ox[2], oy[2]);
                op[2] = make_float4(oz[2], ox[3], oy[3], oz[3]);
            } else {
#pragma unroll
                for (int v = 0; v < VPT; ++v)
                    if (v0 + v < (long long)V) {
                        ((float*)out)[base + v * 3 + 0] = ox[v];
                        ((float*)out)[base + v * 3 + 1] = oy[v];
                        ((float*)out)[base + v * 3 + 2] = oz[v];
                    }
            }
        } else {
            if (full) {
                uint2* op = (uint2*)((bf16*)out + base);      // 8B-aligned
                op[0] = make_uint2(packbf(ox[0], oy[0]), packbf(oz[0], ox[1]));
                op[1] = make_uint2(packbf(oy[1], oz[1]), packbf(ox[2], oy[2]));
                op[2] = make_uint2(packbf(oz[2], ox[3]), packbf(oy[3], oz[3]));
            } else {
#pragma unroll
                for (int v = 0; v < VPT; ++v)
                    if (v0 + v < (long long)V) {
                        st<BF>(out, base + v * 3 + 0, ox[v]);
                        st<BF>(out, base + v * 3 + 1, oy[v]);
                        st<BF>(out, base + v * 3 + 2, oz[v]);
                    }
            }
        }
    }
}

__global__ void __launch_bounds__(256) lbs_all(
    const void* __restrict__ verts,
    const void* __restrict__ joints,
    const void* __restrict__ weights,
    const void* __restrict__ disp,
    const void* __restrict__ rdis,
    PosePtrs pp,
    void* __restrict__ out,
    int V)
{
    __shared__ __align__(16) float sA[P_CNT * J_CNT * 12];   // 17664 B
    __shared__ float sPose[11 * P_CNT * 3];                  // 2112 B
    __shared__ float sSh[P_CNT * 3];
    __shared__ int   sFlag;

    if (threadIdx.x == 0) {
        // dtype detect via sum(weights row r)==1 invariant, rows 0..3
        const float* wf = (const float*)weights;
        const bf16*  wb = (const bf16*)weights;
        bool ok_f = true, ok_b = true;
        for (int r = 0; r < 4; ++r) {
            float sf = 0.f, sb = 0.f;
            for (int j = 0; j < J_CNT; ++j) {
                sf += wf[r * J_CNT + j];
                sb += __bfloat162float(wb[r * J_CNT + j]);
            }
            if (!(fabsf(sf - 1.f) < 0.02f)) ok_f = false;   // NaN-safe
            if (!(fabsf(sb - 1.f) < 0.10f)) ok_b = false;
        }
        sFlag = (!ok_f && ok_b) ? 1 : 0;
    }
    __syncthreads();
    if (sFlag)
        run<true >(verts, joints, weights, disp, rdis, pp, out, V, sA, sPose, sSh);
    else
        run<false>(verts, joints, weights, disp, rdis, pp, out, V, sA, sPose, sSh);
}

extern "C" void kernel_launch(void* const* d_in, const int* in_sizes, int n_in,
                              void* d_out, int out_size, void* d_ws, size_t ws_size,
                              hipStream_t stream) {
    const void* verts   = d_in[0];  // (1,V,3)
    const void* joints  = d_in[1];  // (1,23,3)
    const void* weights = d_in[2];  // (V,23)
    const void* disp    = d_in[3];  // (16,1,3)
    const void* rdis    = d_in[4];  // (16,3)
    PosePtrs pp;
    for (int i = 0; i < 11; ++i) pp.p[i] = d_in[5 + i];

    int V = in_sizes[0] / 3;  // 500000
    int G = (V + VB - 1) / VB;
    lbs_all<<<G, 256, 0, stream>>>(verts, joints, weights, disp, rdis, pp, d_out, V);
}